// Round 7
// baseline (182.598 us; speedup 1.0000x reference)
//
#include <hip/hip_runtime.h>

#define LTAG 64
#define RWAVES 4                      // recurrence waves (16 prev-tags each)
#define NTHR ((RWAVES + 1) * 64)      // +1 producer wave
#define RING 16                       // x ring slots (producer runs 4 ahead)
#define L2E 1.4426950408889634f
#define LN2 0.6931471805599453f

// v_exp_f32: 2^x ; v_log_f32: log2(x)
__device__ __forceinline__ float exp2_fast(float x) { return __builtin_amdgcn_exp2f(x); }
__device__ __forceinline__ float log2_fast(float x) { return __builtin_amdgcn_logf(x); }

__device__ __forceinline__ float readlane_f(float v, int lane) {
    return __int_as_float(__builtin_amdgcn_readlane(__float_as_int(v), lane));
}

#define RAW_BARRIER() asm volatile("s_waitcnt lgkmcnt(0)\n\ts_barrier" ::: "memory")

// ROUND-7 STRUCTURE — producer/consumer wave split.
//
// Diagnosis across rounds 3-6: a stubborn ~600 cy/step floor with ~200-580 cy
// of stall survived every VALU/LDS restructure. The common element: each wave
// consumed one fresh 256B line of X per step, and the compiler is free to
// merge its s_waitcnt to vmcnt(0) (it does so around barriers/LDS waits),
// putting ~100-300cy of HBM latency ON the serial chain regardless of the
// register-ring prefetch distance. C++ gives no control over vmcnt placement.
//
// Fix: wave 4 is a dedicated x-PRODUCER streaming X into a 16-slot LDS ring,
// 4+ steps ahead of consumption; waves 0-3 run the recurrence with ZERO
// global loads in their loop -> the compiler emits no vmcnt waits there at
// all. Pessimal wait placement now stalls only the producer, which has
// ~580cy/step of slack. Sync = the existing single raw barrier per step
// (lgkmcnt(0)+s_barrier: never drains vmcnt -> producer loads stay in
// flight across barriers).
//
// Recurrence (exp-domain, rounds 2-6 verified): A[n]=exp2(alpha[n]*L2E-SH),
//   A'[n] = (sum_p A[p]*Etr[p][n]) * g[n],  g[n]=exp2(x_t[n]*L2E+c2[n]).
// Each of the 4 waves holds the FULL A at lane n (redundant compute kills
// the A-broadcast): per step: 16 batched readlanes + 16 fmac -> partial;
// ds_write partial; barrier; 4 stride-64 b32 reads (2 lanes/bank, free);
// 3 adds; *g. g is pipelined one step: x for step t+1 is ds_read from the
// ring during step t, so its exp2 is fully off-chain.
// Exact power-of-2 rescale every 4 steps (growth <2^19/step, spread ~2^35;
// 35+4*19<127), bit-identical in all waves. Tag-B (lane 0) column fully
// masked (-10000): g[B]==0 so A[B]==0 throughout; final value recovered
// analytically from the last step's s (lane-0 Etr column is all-ones after
// c2 normalization): alpha_T[B] = (log2 s_B + x*L2E + c2_B + SH)*LN2.
__global__ __launch_bounds__(NTHR) void crf_forward_kernel(
    const float* __restrict__ X, const float* __restrict__ trans,
    float* __restrict__ out, int T) {
    const int tid = threadIdx.x;
    const int lane = tid & 63;
    const int wid = __builtin_amdgcn_readfirstlane(tid >> 6);
    const int b = blockIdx.x;
    const float* xb = X + (size_t)b * T * LTAG + lane;

    __shared__ __align__(16) float xring[RING][LTAG];
    __shared__ __align__(16) float part[2][RWAVES * LTAG];

    if (wid == RWAVES) {
        // ================= producer wave =================
        // prologue: fill slots 0..3 directly, start reg ring 2 steps deep
        {
            float v0 = xb[(size_t)(0 < T ? 0 : T - 1) * LTAG];
            float v1 = xb[(size_t)(1 < T ? 1 : T - 1) * LTAG];
            float v2 = xb[(size_t)(2 < T ? 2 : T - 1) * LTAG];
            float v3 = xb[(size_t)(3 < T ? 3 : T - 1) * LTAG];
            xring[0][lane] = v0; xring[1][lane] = v1;
            xring[2][lane] = v2; xring[3][lane] = v3;
        }
        float ra = xb[(size_t)(4 < T ? 4 : T - 1) * LTAG];   // for step 0
        float rb = xb[(size_t)(5 < T ? 5 : T - 1) * LTAG];   // for step 1
        __syncthreads();  // prologue only; vmcnt drain harmless here

        // invariant: at step t, reg (t&1) holds x[min(t+4, T-1)]
        int t = 0;
        for (; t + 2 <= T; t += 2) {
            xring[(t + 4) & (RING - 1)][lane] = ra;
            { int i = t + 6; i = i < T ? i : T - 1; ra = xb[(size_t)i * LTAG]; }
            RAW_BARRIER();
            xring[(t + 5) & (RING - 1)][lane] = rb;
            { int i = t + 7; i = i < T ? i : T - 1; rb = xb[(size_t)i * LTAG]; }
            RAW_BARRIER();
        }
        if (t < T) {  // odd-T tail (not hit at T=512)
            xring[(t + 4) & (RING - 1)][lane] = ra;
            RAW_BARRIER();
        }
    } else {
        // ================= recurrence waves =================
        // per-lane column max over ALL p, + this wave's 16 Etr entries
        float c2 = -3.0e38f;
#pragma unroll
        for (int p = 0; p < LTAG; ++p)
            c2 = fmaxf(c2, trans[p * LTAG + lane] * L2E);
        const int pbase = wid * 16;
        float etr16[16];
#pragma unroll
        for (int i = 0; i < 16; ++i)
            etr16[i] = exp2_fast(trans[(pbase + i) * LTAG + lane] * L2E - c2);

        // init: alpha = NEG except tag B (lane 0) = 0
        float A = (lane == 0) ? 1.0f : 0.0f;
        float SH = 0.0f;
        float sB = 1.0f, xB = 0.0f, shB = 0.0f;  // lane-0 (tag B) fixup state

        __syncthreads();            // matches producer prologue sync
        float xv = xring[0][lane];  // x for step 0 (slot 0 filled in prologue)
        int buf = 0;

// one step; x for step t+1 is ds_read NOW (one barrier of slack -> its
// latency and g's exp2 are fully off the serial chain)
#define STEP(t_, DO_RESCALE)                                                  \
    {                                                                         \
        const float xcur = xv;                                                \
        xv = xring[((t_) + 1) & (RING - 1)][lane];                            \
        const float g = exp2_fast(fmaf(xcur, L2E, c2));                       \
        float ub[16];                                                         \
        _Pragma("unroll") for (int i = 0; i < 16; ++i)                        \
            ub[i] = readlane_f(A, pbase + i);                                 \
        float q0 = 0.f, q1 = 0.f, q2 = 0.f, q3 = 0.f;                         \
        _Pragma("unroll") for (int i = 0; i < 16; i += 4) {                   \
            q0 = fmaf(ub[i + 0], etr16[i + 0], q0);                           \
            q1 = fmaf(ub[i + 1], etr16[i + 1], q1);                           \
            q2 = fmaf(ub[i + 2], etr16[i + 2], q2);                           \
            q3 = fmaf(ub[i + 3], etr16[i + 3], q3);                           \
        }                                                                     \
        part[buf][(wid << 6) + lane] = (q0 + q1) + (q2 + q3);                 \
        RAW_BARRIER();                                                        \
        const float s = (part[buf][lane] + part[buf][64 + lane]) +            \
                        (part[buf][128 + lane] + part[buf][192 + lane]);      \
        sB = s; xB = xcur; shB = SH;                                          \
        A = s * g;                                                            \
        if (DO_RESCALE) {                                                     \
            /* wave-uniform EXACT power-of-2 rescale; identical in all */     \
            /* waves; samples avoid lane 0 (A[0]==0 in exp domain) */         \
            float mm = fmaxf(readlane_f(A, 2), readlane_f(A, 19));            \
            mm = fmaxf(mm, readlane_f(A, 28));                                \
            mm = fmaxf(mm, fmaxf(readlane_f(A, 37), readlane_f(A, 53)));      \
            int eb2 = (__float_as_int(mm) >> 23) & 0xff;                      \
            eb2 = eb2 < 1 ? 1 : eb2;                                          \
            A *= __int_as_float((254 - eb2) << 23); /* *=2^(127-eb), exact */ \
            SH += (float)(eb2 - 127);                                         \
        }                                                                     \
        buf ^= 1;                                                             \
    }

        int t = 0;
        for (; t + 4 <= T; t += 4) {
            STEP(t + 0, false);
            STEP(t + 1, false);
            STEP(t + 2, false);
            STEP(t + 3, true);
        }
        for (; t < T; ++t) STEP(t, false);  // tail (not hit at T=512)
#undef STEP

        float res;
        if (lane == 0) {
            // tag B analytic fixup (see header comment)
            res = (log2_fast(sB) + fmaf(xB, L2E, c2) + shB) * LN2;
        } else {
            res = (log2_fast(A) + SH) * LN2;
        }
        if (wid == 0) out[b * LTAG + lane] = res;  // waves identical; w0 writes
    }
}

extern "C" void kernel_launch(void* const* d_in, const int* in_sizes, int n_in,
                              void* d_out, int out_size, void* d_ws, size_t ws_size,
                              hipStream_t stream) {
    const float* X = (const float*)d_in[0];
    const float* trans = (const float*)d_in[1];
    float* out = (float*)d_out;

    const int B = out_size / LTAG;           // 256
    const int T = in_sizes[0] / (B * LTAG);  // 512

    crf_forward_kernel<<<B, NTHR, 0, stream>>>(X, trans, out, T);
}